// Round 6
// baseline (48321.829 us; speedup 1.0000x reference)
//
#include <hip/hip_runtime.h>
#include <hip/hip_cooperative_groups.h>

namespace cg = cooperative_groups;
typedef unsigned long long u64;

#define NN 2048
#define T_TOTAL 16384
#define WASH 200
#define GRID 128
#define BLOCK 512
#define WAVES (BLOCK / 64)                      // 8
#define ROWS_PER_BLOCK (NN / GRID)              // 16
#define ROWS_PER_WAVE (ROWS_PER_BLOCK / WAVES)  // 2
#define COLS_PER_LANE (NN / 64)                 // 32
#define PPT (NN / BLOCK)                        // 4 tagged pairs per thread

// Tagged-pair dataflow sync (no barriers, no fences, no RMW, no sentinels):
// state element = (float_bits << 32) | step_tag, written by ONE relaxed
// agent-scope 8B atomic store (tear-free; producer's LAST instruction).
// Consumer at step t polls its 4 slots of buffer[t&1] until all tags == t;
// the poll IS the data load -> detection and fetch share one MALL trip.
// Skew proof: any block reaches step t only after observing ALL tags == t,
// which requires every block to have completed its step-(t-1) polls; a
// tag-(t+2) overwrite of tag-t data requires all blocks to have completed
// their step-t polls -> no consumer can still be waiting on tag t. Two
// buffers suffice. ABA across graph replays: stale tags are 16383/16384 or
// 0xAAAAAAAA poison, never equal to the polled tag at that slot/step.

__device__ __forceinline__ float fast_tanh(float x) {
    // tanh(x) = 1 - 2/(e^{2x}+1);  e^{2x} = exp2(x * 2/ln2)  (v_exp_f32)
    float e = exp2f(x * 2.88539008177792681f);
    return 1.0f - 2.0f / (e + 1.0f);
}

__global__ __launch_bounds__(BLOCK, 1)
void esn_kernel(const float* __restrict__ u,
                const float* __restrict__ w_in,
                const float* __restrict__ w_res,
                const float* __restrict__ w_out,
                const float* __restrict__ w_out_mask,
                float* __restrict__ out,       // d_out: T_TOTAL - WASH floats
                u64* __restrict__ pairs,       // ws: 2*NN tagged state (dbuf)
                float* __restrict__ partial,   // ws: T_TOTAL*GRID floats
                int use_partial)
{
    const int b    = blockIdx.x;
    const int tid  = threadIdx.x;
    const int wave = tid >> 6;
    const int lane = tid & 63;
    const int r0   = b * ROWS_PER_BLOCK + wave * ROWS_PER_WAVE;

    // ---- W into registers: wave owns 2 rows, lane holds cols lane+64k ----
    float wreg[ROWS_PER_WAVE][COLS_PER_LANE];
#pragma unroll
    for (int r = 0; r < ROWS_PER_WAVE; ++r) {
        const float* wrow = w_res + (size_t)(r0 + r) * NN;
#pragma unroll
        for (int k = 0; k < COLS_PER_LANE; ++k)
            wreg[r][k] = wrow[lane + 64 * k];
    }
    const int   myr   = lane & (ROWS_PER_WAVE - 1);   // lane<RPW owns row r0+myr
    const float win_m = w_in[r0 + myr];
    const float c_m   = w_out[r0 + myr] * w_out_mask[r0 + myr];

    // ---- publish x_0 = 0 tagged 0 for own rows (self-synchronizing init) ----
    if (tid < ROWS_PER_BLOCK)
        __hip_atomic_store(&pairs[b * ROWS_PER_BLOCK + tid], 0ull,
                           __ATOMIC_RELAXED, __HIP_MEMORY_SCOPE_AGENT);

    __shared__ float xs[NN];
    __shared__ float pout[2][ROWS_PER_BLOCK];

    for (int t = 0; t < T_TOTAL; ++t) {
        const u64* __restrict__ bcur  = pairs + (size_t)(t & 1) * NN;
        u64*       __restrict__ bnext = pairs + (size_t)((t + 1) & 1) * NN;
        const unsigned tg = (unsigned)t;

        const float ut = u[t];   // in flight during the poll

        // ---- poll own 4 slots: detection IS the data load ----
        u64 v[PPT];
        for (;;) {
#pragma unroll
            for (int j = 0; j < PPT; ++j)
                v[j] = __hip_atomic_load(&bcur[tid + BLOCK * j],
                                         __ATOMIC_RELAXED,
                                         __HIP_MEMORY_SCOPE_AGENT);
            bool ok = true;
#pragma unroll
            for (int j = 0; j < PPT; ++j)
                ok &= ((unsigned)v[j] == tg);
            if (ok) break;
        }
#pragma unroll
        for (int j = 0; j < PPT; ++j)
            xs[tid + BLOCK * j] = __uint_as_float((unsigned)(v[j] >> 32));

        __syncthreads();   // the ONLY barrier per step

        // deferred: flush PREVIOUS step's output partial (other pout half)
        if (tid == 0 && t > 0) {
            const float* pp = pout[(t - 1) & 1];
            float pb = 0.0f;
#pragma unroll
            for (int i = 0; i < ROWS_PER_BLOCK; ++i) pb += pp[i];
            if (use_partial) partial[(size_t)(t - 1) * GRID + b] = pb;
            else if (t - 1 >= WASH) atomicAdd(&out[t - 1 - WASH], pb);
        }

        // ---- per-lane x slice + 2 row dot-products from register W ----
        float xv[COLS_PER_LANE];
#pragma unroll
        for (int k = 0; k < COLS_PER_LANE; ++k)
            xv[k] = xs[lane + 64 * k];

        float s[ROWS_PER_WAVE];
#pragma unroll
        for (int r = 0; r < ROWS_PER_WAVE; ++r) {
            float acc = 0.0f;
#pragma unroll
            for (int k = 0; k < COLS_PER_LANE; ++k)
                acc = fmaf(wreg[r][k], xv[k], acc);
            s[r] = acc;
        }
#pragma unroll
        for (int r = 0; r < ROWS_PER_WAVE; ++r) {
#pragma unroll
            for (int off = 32; off > 0; off >>= 1)
                s[r] += __shfl_xor(s[r], off, 64);
        }

        // ---- parallel finish: lane 0/1 each own one row; tagged store is
        //      the wave's LAST memory op (fire-and-forget publish) ----
        if (lane < ROWS_PER_WAVE) {
            float sm = (lane == 0) ? s[0] : s[1];
            float xn = fast_tanh(fmaf(win_m, ut, sm));
            pout[t & 1][wave * ROWS_PER_WAVE + myr] = c_m * xn;
            u64 pk = ((u64)__float_as_uint(xn) << 32) | (u64)(tg + 1u);
            __hip_atomic_store(&bnext[r0 + myr], pk,
                               __ATOMIC_RELAXED, __HIP_MEMORY_SCOPE_AGENT);
        }
    }

    // tail: flush output partial for the last step
    __syncthreads();
    if (tid == 0) {
        const float* pp = pout[(T_TOTAL - 1) & 1];
        float pb = 0.0f;
#pragma unroll
        for (int i = 0; i < ROWS_PER_BLOCK; ++i) pb += pp[i];
        if (use_partial) partial[(size_t)(T_TOTAL - 1) * GRID + b] = pb;
        else atomicAdd(&out[T_TOTAL - 1 - WASH], pb);
    }

    cg::this_grid().sync();   // once; publishes partial[] for phase 2

    // ---- phase 2: deterministic reduction of per-block partials ----
    if (use_partial) {
        for (int t = WASH + b * BLOCK + tid; t < T_TOTAL; t += GRID * BLOCK) {
            const float* pr = partial + (size_t)t * GRID;
            float ssum = 0.0f;
            for (int g = 0; g < GRID; ++g) ssum += pr[g];
            out[t - WASH] = ssum;
        }
    }
}

extern "C" void kernel_launch(void* const* d_in, const int* in_sizes, int n_in,
                              void* d_out, int out_size, void* d_ws, size_t ws_size,
                              hipStream_t stream) {
    const float* u          = (const float*)d_in[0];
    const float* w_in       = (const float*)d_in[1];
    const float* w_res      = (const float*)d_in[2];
    const float* w_out      = (const float*)d_in[3];
    const float* w_out_mask = (const float*)d_in[4];
    float* out = (float*)d_out;

    u64*   pairs   = (u64*)d_ws;                          // 2*NN u64 = 32 KB
    float* partial = (float*)((u64*)d_ws + 2 * NN);       // T_TOTAL*GRID floats
    size_t need = 2 * NN * sizeof(u64) + (size_t)T_TOTAL * GRID * sizeof(float);
    int use_partial = (ws_size >= need) ? 1 : 0;

    // zero output (needed for atomic fallback; harmless otherwise)
    (void)hipMemsetAsync(d_out, 0, (size_t)out_size * sizeof(float), stream);

    void* args[] = {(void*)&u, (void*)&w_in, (void*)&w_res, (void*)&w_out,
                    (void*)&w_out_mask, (void*)&out, (void*)&pairs,
                    (void*)&partial, (void*)&use_partial};
    (void)hipLaunchCooperativeKernel((void*)esn_kernel, dim3(GRID), dim3(BLOCK),
                                     args, 0, stream);
}